// Round 6
// baseline (168.106 us; speedup 1.0000x reference)
//
#include <hip/hip_runtime.h>
#include <math.h>

#define Bn 4
#define Cn 64
#define On 64
#define Hn 128
#define Wn 128
#define HWn (Hn * Wn)

typedef __attribute__((ext_vector_type(8))) short s16x8;
typedef __attribute__((ext_vector_type(4))) float f32x4;

__device__ __forceinline__ unsigned short f2bf(float f) {
    unsigned u = __float_as_uint(f);
    u += 0x7fffu + ((u >> 16) & 1u);  // RTNE (finite values)
    return (unsigned short)(u >> 16);
}
__device__ __forceinline__ float bf2f(unsigned short u) {
    return __uint_as_float(((unsigned)u) << 16);
}

// ---------------------------------------------------------------------------
// K1: z=0: x -> xt [B,HW,C] bf16; z=1: feat -> ft; z=2: weights ->
//   wdT2 [2s][9k][64oc][32c] bf16, woT2 [2s][9k][32oc][32c] bf16 (oc>=27 -> 0)
// ---------------------------------------------------------------------------
__global__ __launch_bounds__(256) void transpose_all(const float* __restrict__ x,
                                                     const float* __restrict__ feat,
                                                     const float* __restrict__ wdef,
                                                     const float* __restrict__ woff,
                                                     ushort* __restrict__ xt,
                                                     ushort* __restrict__ ft,
                                                     ushort* __restrict__ wdT2,
                                                     ushort* __restrict__ woT2) {
    int t = threadIdx.x;
    if (blockIdx.z == 2) {
        int id = (blockIdx.y * gridDim.x + blockIdx.x) * 256 + t;
        if (id < 36864) {  // [s][k][oc 64][c 32]
            int c2 = id & 31, oc = (id >> 5) & 63, ks = id >> 11;
            int k = ks % 9, s = ks / 9;
            wdT2[id] = f2bf(wdef[(oc * 64 + s * 32 + c2) * 9 + k]);
        } else if (id < 55296) {  // [s][k][oc 32][c 32]
            int i2 = id - 36864;
            int c2 = i2 & 31, oc = (i2 >> 5) & 31, ks = i2 >> 10;
            int k = ks % 9, s = ks / 9;
            woT2[i2] = (oc < 27) ? f2bf(woff[(oc * 64 + s * 32 + c2) * 9 + k]) : (ushort)0;
        }
        return;
    }
    __shared__ float tile[64][65];
    const float* src = blockIdx.z ? feat : x;
    ushort* dst0 = blockIdx.z ? ft : xt;
    int b = blockIdx.y, hw0 = blockIdx.x * 64;
    int lane = t & 63, grp = t >> 6;
    const float* xb = src + (size_t)b * Cn * HWn;
#pragma unroll
    for (int i = 0; i < 16; ++i) {
        int c = grp * 16 + i;
        tile[lane][c] = xb[(size_t)c * HWn + hw0 + lane];  // coalesced along hw
    }
    __syncthreads();
#pragma unroll
    for (int jj = 0; jj < 2; ++jj) {
        int px = jj * 32 + (t >> 3), ch = t & 7;
        s16x8 p;
#pragma unroll
        for (int j = 0; j < 8; ++j) p[j] = (short)f2bf(tile[px][ch * 8 + j]);
        *(s16x8*)(dst0 + ((size_t)(b * HWn + hw0 + px)) * Cn + ch * 8) = p;  // coalesced
    }
}

// ---------------------------------------------------------------------------
// K2 (fused, cacheflow): R16. NO window staging, NO DMA, NO vote.
//  Rationale: with the XCD band swizzle each XCD's band touches ~1 MB of xt
//  and ~1 MB of ft — both resident in its private 4 MB L2. LDS-staging
//  L2-fit data was pure overhead (3.4x window overfetch + drain barriers +
//  47 KB LDS -> 3 blocks/CU with a 33% block tail).
//  New structure per block (2 rows x 32 cols, 4 waves):
//   - GEMM1: om conv, A-operands per-tap DIRECT from global ft (L1/L2-hot),
//     weights from global woT2. bias+sigmoid -> s_om (6912 B).
//   - barrier; lanes read their 27 om values; barrier.
//   - GEMM2: general bilinear-gather path direct from global xt (this was
//     the "slow path" — identical arithmetic to the old fast path), weights
//     from global wdT2.
//   - barrier; s_out overlay; coalesced store.
//  LDS 47104 -> 17408 B; barriers 5 -> 3; occupancy VGPR-limited
//  (~5-6 waves/SIMD = 20-24 waves/CU), zero block tail.
// ---------------------------------------------------------------------------
__global__ __launch_bounds__(256, 3) void mega_kernel(const ushort* __restrict__ xt,
                                                      const ushort* __restrict__ ft,
                                                      const ushort* __restrict__ wdT2,
                                                      const ushort* __restrict__ woT2,
                                                      const float* __restrict__ b_off,
                                                      const float* __restrict__ b_def,
                                                      float* __restrict__ out) {
    __shared__ __align__(16) char smem[17408];
    float* s_om = (float*)smem;               // [27][64] f32 (6912 B)
    float* s_out = (float*)smem;              // [64][68] f32 overlay (17408 B)

    int t = threadIdx.x;
    int wv = t >> 6, l = t & 63;
    int q = l >> 4, r = l & 15;
    int blk = (blockIdx.x & 7) * 128 + (blockIdx.x >> 3);  // XCD band swizzle
    int b = blk >> 8;
    int gi = blk & 255;
    int h = (gi >> 2) << 1;           // even row; block covers rows h, h+1
    int wbase = (gi & 3) << 5;        // 32-col strip
    int rowoff = wv >> 1, pxh = wv & 1;
    int hrow = h + rowoff;
    int pxi = pxh * 16 + r;           // col within strip [0,32)
    const ushort* xt_b = xt + (size_t)b * HWn * Cn;
    const ushort* ft_b = ft + (size_t)b * HWn * Cn;

    f32x4 zero = {0.f, 0.f, 0.f, 0.f};
    s16x8 zz = {0, 0, 0, 0, 0, 0, 0, 0};

    // ---- phase 1: om GEMM, ft direct from global (L1/L2-hot) ----
    f32x4 acc2[2];
    acc2[0] = zero; acc2[1] = zero;
    {
        int pxg = wv * 16 + r;            // GEMM M-index (block-local px)
        int rg = pxg >> 5, cg = pxg & 31;
#pragma unroll 3
        for (int k = 0; k < 9; ++k) {
            int dy = k / 3 - 1, dx = k % 3 - 1;
            int y = h + rg + dy;
            bool yv = (y >= 0) && (y < Hn);
            int xx = wbase + cg + dx;
            bool valid = yv && (xx >= 0) && (xx < Wn);
            int ys_ = min(max(y, 0), Hn - 1);
            int xs_ = min(max(xx, 0), Wn - 1);
            const ushort* ap = ft_b + (size_t)(ys_ * Wn + xs_) * Cn;
#pragma unroll
            for (int s = 0; s < 2; ++s) {
                s16x8 av = *(const s16x8*)(ap + (s * 4 + q) * 8);
                av = valid ? av : zz;
#pragma unroll
                for (int ot = 0; ot < 2; ++ot) {
                    s16x8 bv = *(const s16x8*)(woT2 + (size_t)s * 9216
                                               + (size_t)(k * 32 + ot * 16 + r) * 32 + q * 8);
                    acc2[ot] = __builtin_amdgcn_mfma_f32_16x16x32_bf16(av, bv, acc2[ot], 0, 0, 0);
                }
            }
        }
    }

    // ---- bounce: bias + sigmoid -> s_om[27][64] ----
#pragma unroll
    for (int ot = 0; ot < 2; ++ot) {
        int oc = ot * 16 + r;
        if (oc < 27) {
            float bo = b_off[oc];
#pragma unroll
            for (int reg = 0; reg < 4; ++reg) {
                int p = wv * 16 + q * 4 + reg;
                float v = acc2[ot][reg] + bo;
                if (oc >= 18) v = 1.f / (1.f + __expf(-v));
                s_om[oc * 64 + p] = v;
            }
        }
    }
    __syncthreads();  // (1) s_om visible

    // ---- per-lane om values ----
    float omv[27];
#pragma unroll
    for (int o = 0; o < 27; ++o) omv[o] = s_om[o * 64 + wv * 16 + r];
    __syncthreads();  // (2) omv reads done (s_out overlay safe after GEMM2)

    // ---- phase 2: deform gather + main GEMM, xt direct from global ----
    f32x4 acc[4];
    acc[0] = zero; acc[1] = zero; acc[2] = zero; acc[3] = zero;
#pragma unroll 1
    for (int k = 0; k < 9; ++k) {
        float ys = (float)(hrow + k / 3 - 1) + omv[9 + k];
        float xs = (float)(wbase + pxi + k % 3 - 1) + omv[k];
        float mv = omv[18 + k];
        float y0f = floorf(ys), x0f = floorf(xs);
        float fy = ys - y0f, fx = xs - x0f;
        int y0 = (int)y0f, x0 = (int)x0f;
        float g[4];
        int a[4];
#pragma unroll
        for (int n = 0; n < 4; ++n) {
            int yy = y0 + (n >> 1), xx = x0 + (n & 1);
            bool valid = (yy >= 0) && (yy < Hn) && (xx >= 0) && (xx < Wn);
            float wgt = ((n >> 1) ? fy : 1.f - fy) * ((n & 1) ? fx : 1.f - fx) * mv;
            g[n] = valid ? wgt : 0.f;
            int yc = min(max(yy, 0), Hn - 1), xc = min(max(xx, 0), Wn - 1);
            a[n] = (yc * Wn + xc) * Cn;
        }
#pragma unroll
        for (int s = 0; s < 2; ++s) {
            int c = s * 32 + q * 8;
            s16x8 q0 = *(const s16x8*)(xt_b + a[0] + c);
            s16x8 q1 = *(const s16x8*)(xt_b + a[1] + c);
            s16x8 q2 = *(const s16x8*)(xt_b + a[2] + c);
            s16x8 q3 = *(const s16x8*)(xt_b + a[3] + c);
            s16x8 af;
#pragma unroll
            for (int j = 0; j < 8; ++j) {
                float rr = g[0] * bf2f((unsigned short)q0[j]) + g[1] * bf2f((unsigned short)q1[j])
                         + g[2] * bf2f((unsigned short)q2[j]) + g[3] * bf2f((unsigned short)q3[j]);
                af[j] = (short)f2bf(rr);
            }
#pragma unroll
            for (int ot = 0; ot < 4; ++ot) {
                s16x8 bv = *(const s16x8*)(wdT2 + (size_t)s * 18432
                                           + (size_t)(k * 64 + ot * 16 + r) * 32 + q * 8);
                acc[ot] = __builtin_amdgcn_mfma_f32_16x16x32_bf16(af, bv, acc[ot], 0, 0, 0);
            }
        }
    }
    __syncthreads();  // (3) all omv/s_om consumers done; region becomes s_out

    // ---- epilogue: bias + ReLU, stage [oc][px64], coalesced store ----
#pragma unroll
    for (int ot = 0; ot < 4; ++ot) {
        int oc = ot * 16 + r;
        float bv = b_def[oc];
        f32x4 vv;
#pragma unroll
        for (int reg = 0; reg < 4; ++reg) vv[reg] = fmaxf(acc[ot][reg] + bv, 0.f);
        *(f32x4*)&s_out[oc * 68 + rowoff * 32 + pxh * 16 + q * 4] = vv;
    }
    __syncthreads();
    {
        int px = t & 63, og = t >> 6;
        int rg = h + (px >> 5);
        float* ob = out + ((size_t)b * On) * HWn + rg * Wn + wbase + (px & 31);
#pragma unroll
        for (int j = 0; j < 16; ++j) {
            int oc = og * 16 + j;
            ob[(size_t)oc * HWn] = s_out[oc * 68 + px];
        }
    }
}

// ---------------------------------------------------------------------------
extern "C" void kernel_launch(void* const* d_in, const int* in_sizes, int n_in,
                              void* d_out, int out_size, void* d_ws, size_t ws_size,
                              hipStream_t stream) {
    const float* x = (const float*)d_in[0];
    const float* feat = (const float*)d_in[1];
    const float* w_off = (const float*)d_in[2];
    const float* b_off = (const float*)d_in[3];
    const float* w_def = (const float*)d_in[4];
    const float* b_def = (const float*)d_in[5];
    float* out = (float*)d_out;

    char* ws = (char*)d_ws;
    ushort* xt = (ushort*)ws;                           // 8 MB [B,HW,C] bf16
    ushort* ft = (ushort*)(ws + 8388608);               // 8 MB [B,HW,C] bf16
    ushort* wdT2 = (ushort*)(ws + 16777216);            // 73728 B [2][9][64][32]
    ushort* woT2 = (ushort*)(ws + 16850944);            // 36864 B [2][9][32][32]

    hipLaunchKernelGGL(transpose_all, dim3(HWn / 64, Bn, 3), dim3(256), 0, stream,
                       x, feat, w_def, w_off, xt, ft, wdT2, woT2);
    hipLaunchKernelGGL(mega_kernel, dim3((Bn * HWn) / 64), dim3(256), 0, stream,
                       xt, ft, wdT2, woT2, b_off, b_def, out);
}

// Round 7
// 134.989 us; speedup vs baseline: 1.2453x; 1.2453x over previous
//
#include <hip/hip_runtime.h>
#include <math.h>

#define Bn 4
#define Cn 64
#define On 64
#define Hn 128
#define Wn 128
#define HWn (Hn * Wn)

typedef __attribute__((ext_vector_type(8))) short s16x8;
typedef __attribute__((ext_vector_type(4))) float f32x4;
typedef __attribute__((ext_vector_type(4))) unsigned int u32x4;

__device__ __forceinline__ unsigned short f2bf(float f) {
    unsigned u = __float_as_uint(f);
    u += 0x7fffu + ((u >> 16) & 1u);  // RTNE (finite values)
    return (unsigned short)(u >> 16);
}
__device__ __forceinline__ float bf2f(unsigned short u) {
    return __uint_as_float(((unsigned)u) << 16);
}
// pack 8 f32 -> 8 bf16 (RNE) via v_cvt_pk_bf16_f32 (4 instr instead of ~32)
__device__ __forceinline__ s16x8 pack8(const float* rr) {
    u32x4 pk;
#pragma unroll
    for (int jj = 0; jj < 4; ++jj) {
        unsigned w;
        asm("v_cvt_pk_bf16_f32 %0, %1, %2" : "=v"(w) : "v"(rr[2 * jj]), "v"(rr[2 * jj + 1]));
        pk[jj] = w;
    }
    return __builtin_bit_cast(s16x8, pk);
}

// ---------------------------------------------------------------------------
// K1: z=0: x -> xt [B,HW,C] bf16; z=1: feat -> ft; z=2: weights ->
//   wdT2 [2s][9k][64oc][32c] bf16, woT2 [2s][9k][32oc][32c] bf16 (oc>=27 -> 0)
// ---------------------------------------------------------------------------
__global__ __launch_bounds__(256) void transpose_all(const float* __restrict__ x,
                                                     const float* __restrict__ feat,
                                                     const float* __restrict__ wdef,
                                                     const float* __restrict__ woff,
                                                     ushort* __restrict__ xt,
                                                     ushort* __restrict__ ft,
                                                     ushort* __restrict__ wdT2,
                                                     ushort* __restrict__ woT2) {
    int t = threadIdx.x;
    if (blockIdx.z == 2) {
        int id = (blockIdx.y * gridDim.x + blockIdx.x) * 256 + t;
        if (id < 36864) {  // [s][k][oc 64][c 32]
            int c2 = id & 31, oc = (id >> 5) & 63, ks = id >> 11;
            int k = ks % 9, s = ks / 9;
            wdT2[id] = f2bf(wdef[(oc * 64 + s * 32 + c2) * 9 + k]);
        } else if (id < 55296) {  // [s][k][oc 32][c 32]
            int i2 = id - 36864;
            int c2 = i2 & 31, oc = (i2 >> 5) & 31, ks = i2 >> 10;
            int k = ks % 9, s = ks / 9;
            woT2[i2] = (oc < 27) ? f2bf(woff[(oc * 64 + s * 32 + c2) * 9 + k]) : (ushort)0;
        }
        return;
    }
    __shared__ float tile[64][65];
    const float* src = blockIdx.z ? feat : x;
    ushort* dst0 = blockIdx.z ? ft : xt;
    int b = blockIdx.y, hw0 = blockIdx.x * 64;
    int lane = t & 63, grp = t >> 6;
    const float* xb = src + (size_t)b * Cn * HWn;
#pragma unroll
    for (int i = 0; i < 16; ++i) {
        int c = grp * 16 + i;
        tile[lane][c] = xb[(size_t)c * HWn + hw0 + lane];  // coalesced along hw
    }
    __syncthreads();
#pragma unroll
    for (int jj = 0; jj < 2; ++jj) {
        int px = jj * 32 + (t >> 3), ch = t & 7;
        s16x8 p;
#pragma unroll
        for (int j = 0; j < 8; ++j) p[j] = (short)f2bf(tile[px][ch * 8 + j]);
        *(s16x8*)(dst0 + ((size_t)(b * HWn + hw0 + px)) * Cn + ch * 8) = p;  // coalesced
    }
}

// ---------------------------------------------------------------------------
// K2 (fused): R17 = R15 structure, ft staging removed, cvt_pk packing.
//  R16 lesson: xt gathers MUST go through LDS (direct = 99 µs, vmem-latency
//  bound); but direct global reads are fine for phase-1's 18 L2-hot loads.
//  Per block (2 rows x 32 cols, 4 waves):
//   - issue 7 xt-window DMAs (rows h-2..h+3, 216 lins pad 224) -> in flight
//     under ALL of phase 1 (T14); drained by the bounce barrier.
//   - phase 1: om GEMM, A per-tap DIRECT from global ft (clamped+masked),
//     weights from global woT2. bias+sigmoid -> s_om (separate 6912 B).
//   - barrier (drains DMA + s_om visible); lanes read their 27 om values.
//   - phase 2: vote + bilinear interp from s_win + main GEMM (wdT2 global).
//   - barrier; epilogue via s_out overlay of s_win; barrier; store.
//  LDS 47104 -> 35584 B (4 blocks/CU); barriers 5 -> 3; no vmcnt asm.
//  Interp f2bf bit-twiddle (4 ops/elem) -> v_cvt_pk_bf16_f32 (0.5/elem).
// ---------------------------------------------------------------------------
__global__ __launch_bounds__(256, 3) void mega_kernel(const ushort* __restrict__ xt,
                                                      const ushort* __restrict__ ft,
                                                      const ushort* __restrict__ wdT2,
                                                      const ushort* __restrict__ woT2,
                                                      const float* __restrict__ b_off,
                                                      const float* __restrict__ b_def,
                                                      float* __restrict__ out) {
    __shared__ __align__(16) char smem[35584];
    ushort* s_win = (ushort*)smem;             // xt window: 224 lins * 128 B
    float* s_om = (float*)(smem + 28672);      // [27][64] f32 (6912 B)
    float* s_out = (float*)smem;               // [64][68] f32 overlay of s_win

    int t = threadIdx.x;
    int wv = t >> 6, l = t & 63;
    int q = l >> 4, r = l & 15;
    int blk = (blockIdx.x & 7) * 128 + (blockIdx.x >> 3);  // XCD band swizzle
    int b = blk >> 8;
    int gi = blk & 255;
    int h = (gi >> 2) << 1;           // even row; block covers rows h, h+1
    int wbase = (gi & 3) << 5;        // 32-col strip
    int rowoff = wv >> 1, pxh = wv & 1;
    int hrow = h + rowoff;
    int pxi = pxh * 16 + r;           // col within strip [0,32)
    float pxif = (float)pxi;
    float rowofff = (float)rowoff;
    const ushort* xt_b = xt + (size_t)b * HWn * Cn;
    const ushort* ft_b = ft + (size_t)b * HWn * Cn;

    // ---- (a) DMA xt window (rows h-2..h+3, cols wbase-2..wbase+33) ----
#pragma unroll
    for (int i = 0; i < 7; ++i) {
        int jb = i * 256 + wv * 64;
        int j = jb + l;
        int lin = j >> 3, slot = j & 7;
        int linc = min(lin, 215);
        int cidx = (slot - lin) & 7;  // inverse of read rotation
        int row = linc / 36, col = linc - row * 36;
        int rs = min(max(h - 2 + row, 0), Hn - 1);
        int cs = min(max(wbase - 2 + col, 0), Wn - 1);
        const ushort* gp = xt_b + (size_t)(rs * Wn + cs) * Cn + cidx * 8;
        __builtin_amdgcn_global_load_lds(
            (const __attribute__((address_space(1))) unsigned int*)gp,
            (__attribute__((address_space(3))) unsigned int*)(s_win + (size_t)jb * 8),
            16, 0, 0);
    }

    f32x4 zero = {0.f, 0.f, 0.f, 0.f};
    s16x8 zz = {0, 0, 0, 0, 0, 0, 0, 0};

    // ---- phase 1: om GEMM, ft direct from global (L1/L2-hot) ----
    f32x4 acc2[2];
    acc2[0] = zero; acc2[1] = zero;
    {
        int pxg = wv * 16 + r;            // GEMM M-index (block-local px)
        int rg = pxg >> 5, cg = pxg & 31;
#pragma unroll 3
        for (int k = 0; k < 9; ++k) {
            int dy = k / 3 - 1, dx = k % 3 - 1;
            int y = h + rg + dy;
            bool yv = (y >= 0) && (y < Hn);
            int xx = wbase + cg + dx;
            bool valid = yv && (xx >= 0) && (xx < Wn);
            int ys_ = min(max(y, 0), Hn - 1);
            int xs_ = min(max(xx, 0), Wn - 1);
            const ushort* ap = ft_b + (size_t)(ys_ * Wn + xs_) * Cn;
#pragma unroll
            for (int s = 0; s < 2; ++s) {
                s16x8 av = *(const s16x8*)(ap + (s * 4 + q) * 8);
                av = valid ? av : zz;
#pragma unroll
                for (int ot = 0; ot < 2; ++ot) {
                    s16x8 bv = *(const s16x8*)(woT2 + (size_t)s * 9216
                                               + (size_t)(k * 32 + ot * 16 + r) * 32 + q * 8);
                    acc2[ot] = __builtin_amdgcn_mfma_f32_16x16x32_bf16(av, bv, acc2[ot], 0, 0, 0);
                }
            }
        }
    }

    // ---- bounce: bias + sigmoid -> s_om[27][64] ----
#pragma unroll
    for (int ot = 0; ot < 2; ++ot) {
        int oc = ot * 16 + r;
        if (oc < 27) {
            float bo = b_off[oc];
#pragma unroll
            for (int reg = 0; reg < 4; ++reg) {
                int p = wv * 16 + q * 4 + reg;
                float v = acc2[ot][reg] + bo;
                if (oc >= 18) v = 1.f / (1.f + __expf(-v));
                s_om[oc * 64 + p] = v;
            }
        }
    }
    __syncthreads();  // (1) s_om visible; drains xt DMA (vmcnt 0)

    // ---- per-lane om values + vote ----
    float omv[27];
#pragma unroll
    for (int o = 0; o < 27; ++o) omv[o] = s_om[o * 64 + rowoff * 32 + pxi];
    bool okp = true;
#pragma unroll
    for (int k = 0; k < 9; ++k) {
        float uy = (float)(k / 3 - 1) + omv[9 + k];
        float ux = pxif + (float)(k % 3 - 1) + omv[k];
        okp = okp && (uy >= -2.f - rowofff) && (uy < 3.f - rowofff)
                  && (ux >= -2.f) && (ux < 33.f);
    }
    int fast = __all(okp) ? 1 : 0;

    f32x4 acc[4];
    acc[0] = zero; acc[1] = zero; acc[2] = zero; acc[3] = zero;

    if (fast) {
#pragma unroll 3
        for (int k = 0; k < 9; ++k) {
            float uy = (float)(k / 3 - 1) + omv[9 + k];
            float ux = pxif + (float)(k % 3 - 1) + omv[k];
            float mv = omv[18 + k];
            float y0f = floorf(uy), x0f = floorf(ux);
            float fy = uy - y0f, fx = ux - x0f;
            int iy = (int)y0f + 2 + rowoff;  // 0..4
            int ix = (int)x0f + 2;           // 0..34
            int yab = hrow + (int)y0f, xab = wbase + (int)x0f;
            bool vy0 = (yab >= 0) && (yab < Hn);
            bool vy1 = (yab + 1 >= 0) && (yab + 1 < Hn);
            bool vx0 = (xab >= 0) && (xab < Wn);
            bool vx1 = (xab + 1 >= 0) && (xab + 1 < Wn);
            float g0 = (vy0 && vx0) ? (1.f - fy) * (1.f - fx) * mv : 0.f;
            float g1 = (vy0 && vx1) ? (1.f - fy) * fx * mv : 0.f;
            float g2 = (vy1 && vx0) ? fy * (1.f - fx) * mv : 0.f;
            float g3 = (vy1 && vx1) ? fy * fx * mv : 0.f;
            int l0 = iy * 36 + ix, l1 = l0 + 1, l2 = l0 + 36, l3 = l0 + 37;
            // weights for this tap (global, L2-hot): full 64 oc
            s16x8 bw[2][4];
#pragma unroll
            for (int s = 0; s < 2; ++s)
#pragma unroll
                for (int ot = 0; ot < 4; ++ot)
                    bw[s][ot] = *(const s16x8*)(wdT2 + (size_t)s * 18432
                                                + (size_t)(k * 64 + ot * 16 + r) * 32 + q * 8);
            s16x8 af[2];
#pragma unroll
            for (int s = 0; s < 2; ++s) {
                int c = s * 4 + q;  // logical chunk
                s16x8 q0 = *(const s16x8*)&s_win[l0 * 64 + (((c + l0) & 7) << 3)];
                s16x8 q1 = *(const s16x8*)&s_win[l1 * 64 + (((c + l1) & 7) << 3)];
                s16x8 q2 = *(const s16x8*)&s_win[l2 * 64 + (((c + l2) & 7) << 3)];
                s16x8 q3 = *(const s16x8*)&s_win[l3 * 64 + (((c + l3) & 7) << 3)];
                float rr[8];
#pragma unroll
                for (int j = 0; j < 8; ++j) {
                    rr[j] = g0 * bf2f((unsigned short)q0[j]) + g1 * bf2f((unsigned short)q1[j])
                          + g2 * bf2f((unsigned short)q2[j]) + g3 * bf2f((unsigned short)q3[j]);
                }
                af[s] = pack8(rr);
            }
#pragma unroll
            for (int s = 0; s < 2; ++s)
#pragma unroll
                for (int ot = 0; ot < 4; ++ot)
                    acc[ot] = __builtin_amdgcn_mfma_f32_16x16x32_bf16(af[s], bw[s][ot], acc[ot], 0, 0, 0);
        }
    } else {
        // slow path (rare, any-input correct): global gathers + global weights
#pragma unroll 1
        for (int k = 0; k < 9; ++k) {
            float ys = (float)(hrow + k / 3 - 1) + omv[9 + k];
            float xs = (float)(wbase + pxi + k % 3 - 1) + omv[k];
            float mv = omv[18 + k];
            float y0f = floorf(ys), x0f = floorf(xs);
            float fy = ys - y0f, fx = xs - x0f;
            int y0 = (int)y0f, x0 = (int)x0f;
            float g[4];
            int a[4];
#pragma unroll
            for (int n = 0; n < 4; ++n) {
                int yy = y0 + (n >> 1), xx = x0 + (n & 1);
                bool valid = (yy >= 0) && (yy < Hn) && (xx >= 0) && (xx < Wn);
                float wgt = ((n >> 1) ? fy : 1.f - fy) * ((n & 1) ? fx : 1.f - fx) * mv;
                g[n] = valid ? wgt : 0.f;
                int yc = min(max(yy, 0), Hn - 1), xc = min(max(xx, 0), Wn - 1);
                a[n] = (yc * Wn + xc) * Cn;
            }
#pragma unroll
            for (int s = 0; s < 2; ++s) {
                int c = s * 32 + q * 8;
                s16x8 q0 = *(const s16x8*)(xt_b + a[0] + c);
                s16x8 q1 = *(const s16x8*)(xt_b + a[1] + c);
                s16x8 q2 = *(const s16x8*)(xt_b + a[2] + c);
                s16x8 q3 = *(const s16x8*)(xt_b + a[3] + c);
                float rr[8];
#pragma unroll
                for (int j = 0; j < 8; ++j) {
                    rr[j] = g[0] * bf2f((unsigned short)q0[j]) + g[1] * bf2f((unsigned short)q1[j])
                          + g[2] * bf2f((unsigned short)q2[j]) + g[3] * bf2f((unsigned short)q3[j]);
                }
                s16x8 af = pack8(rr);
#pragma unroll
                for (int ot = 0; ot < 4; ++ot) {
                    s16x8 bv = *(const s16x8*)(wdT2 + (size_t)s * 18432
                                               + (size_t)(k * 64 + ot * 16 + r) * 32 + q * 8);
                    acc[ot] = __builtin_amdgcn_mfma_f32_16x16x32_bf16(af, bv, acc[ot], 0, 0, 0);
                }
            }
        }
    }
    __syncthreads();  // (2) all s_win reads done; region becomes s_out

    // ---- epilogue: bias + ReLU, stage [oc][px64], coalesced store ----
#pragma unroll
    for (int ot = 0; ot < 4; ++ot) {
        int oc = ot * 16 + r;
        float bv = b_def[oc];
        f32x4 vv;
#pragma unroll
        for (int reg = 0; reg < 4; ++reg) vv[reg] = fmaxf(acc[ot][reg] + bv, 0.f);
        *(f32x4*)&s_out[oc * 68 + rowoff * 32 + pxh * 16 + q * 4] = vv;
    }
    __syncthreads();  // (3)
    {
        int px = t & 63, og = t >> 6;
        int rg = h + (px >> 5);
        float* ob = out + ((size_t)b * On) * HWn + rg * Wn + wbase + (px & 31);
#pragma unroll
        for (int j = 0; j < 16; ++j) {
            int oc = og * 16 + j;
            ob[(size_t)oc * HWn] = s_out[oc * 68 + px];
        }
    }
}

// ---------------------------------------------------------------------------
extern "C" void kernel_launch(void* const* d_in, const int* in_sizes, int n_in,
                              void* d_out, int out_size, void* d_ws, size_t ws_size,
                              hipStream_t stream) {
    const float* x = (const float*)d_in[0];
    const float* feat = (const float*)d_in[1];
    const float* w_off = (const float*)d_in[2];
    const float* b_off = (const float*)d_in[3];
    const float* w_def = (const float*)d_in[4];
    const float* b_def = (const float*)d_in[5];
    float* out = (float*)d_out;

    char* ws = (char*)d_ws;
    ushort* xt = (ushort*)ws;                           // 8 MB [B,HW,C] bf16
    ushort* ft = (ushort*)(ws + 8388608);               // 8 MB [B,HW,C] bf16
    ushort* wdT2 = (ushort*)(ws + 16777216);            // 73728 B [2][9][64][32]
    ushort* woT2 = (ushort*)(ws + 16850944);            // 36864 B [2][9][32][32]

    hipLaunchKernelGGL(transpose_all, dim3(HWn / 64, Bn, 3), dim3(256), 0, stream,
                       x, feat, w_def, w_off, xt, ft, wdT2, woT2);
    hipLaunchKernelGGL(mega_kernel, dim3((Bn * HWn) / 64), dim3(256), 0, stream,
                       xt, ft, wdT2, woT2, b_off, b_def, out);
}

// Round 8
// 128.216 us; speedup vs baseline: 1.3111x; 1.0528x over previous
//
#include <hip/hip_runtime.h>
#include <math.h>

#define Bn 4
#define Cn 64
#define On 64
#define Hn 128
#define Wn 128
#define HWn (Hn * Wn)

typedef __attribute__((ext_vector_type(8))) short s16x8;
typedef __attribute__((ext_vector_type(4))) float f32x4;

__device__ __forceinline__ unsigned short f2bf(float f) {
    unsigned u = __float_as_uint(f);
    u += 0x7fffu + ((u >> 16) & 1u);  // RTNE (finite values)
    return (unsigned short)(u >> 16);
}
__device__ __forceinline__ float bf2f(unsigned short u) {
    return __uint_as_float(((unsigned)u) << 16);
}

// ---------------------------------------------------------------------------
// K1: z=0: x -> xt [B,HW,C] bf16; z=1: feat -> ft; z=2: weights ->
//   wdT2 [2s][9k][64oc][32c] bf16, woT2 [2s][9k][32oc][32c] bf16 (oc>=27 -> 0)
// ---------------------------------------------------------------------------
__global__ __launch_bounds__(256) void transpose_all(const float* __restrict__ x,
                                                     const float* __restrict__ feat,
                                                     const float* __restrict__ wdef,
                                                     const float* __restrict__ woff,
                                                     ushort* __restrict__ xt,
                                                     ushort* __restrict__ ft,
                                                     ushort* __restrict__ wdT2,
                                                     ushort* __restrict__ woT2) {
    int t = threadIdx.x;
    if (blockIdx.z == 2) {
        int id = (blockIdx.y * gridDim.x + blockIdx.x) * 256 + t;
        if (id < 36864) {  // [s][k][oc 64][c 32]
            int c2 = id & 31, oc = (id >> 5) & 63, ks = id >> 11;
            int k = ks % 9, s = ks / 9;
            wdT2[id] = f2bf(wdef[(oc * 64 + s * 32 + c2) * 9 + k]);
        } else if (id < 55296) {  // [s][k][oc 32][c 32]
            int i2 = id - 36864;
            int c2 = i2 & 31, oc = (i2 >> 5) & 31, ks = i2 >> 10;
            int k = ks % 9, s = ks / 9;
            woT2[i2] = (oc < 27) ? f2bf(woff[(oc * 64 + s * 32 + c2) * 9 + k]) : (ushort)0;
        }
        return;
    }
    __shared__ float tile[64][65];
    const float* src = blockIdx.z ? feat : x;
    ushort* dst0 = blockIdx.z ? ft : xt;
    int b = blockIdx.y, hw0 = blockIdx.x * 64;
    int lane = t & 63, grp = t >> 6;
    const float* xb = src + (size_t)b * Cn * HWn;
#pragma unroll
    for (int i = 0; i < 16; ++i) {
        int c = grp * 16 + i;
        tile[lane][c] = xb[(size_t)c * HWn + hw0 + lane];  // coalesced along hw
    }
    __syncthreads();
#pragma unroll
    for (int jj = 0; jj < 2; ++jj) {
        int px = jj * 32 + (t >> 3), ch = t & 7;
        s16x8 p;
#pragma unroll
        for (int j = 0; j < 8; ++j) p[j] = (short)f2bf(tile[px][ch * 8 + j]);
        *(s16x8*)(dst0 + ((size_t)(b * HWn + hw0 + px)) * Cn + ch * 8) = p;  // coalesced
    }
}

// ---------------------------------------------------------------------------
// K2 (fused): R18 = R17 minus the cvt_pk inline asm (m240: hand-written
//  cvt_pk defeats the scheduler, −37% on VALU-hot loops). Scalar f2bf
//  restored in both interp paths. Everything else identical to R17:
//   - 7 xt-window DMAs in flight under ALL of phase 1 (T14).
//   - phase 1: om GEMM, A per-tap DIRECT from global ft (L2-hot),
//     weights from global woT2. bias+sigmoid -> s_om (6912 B).
//   - barrier (drains DMA + s_om visible); 27 om LDS reads; vote.
//   - phase 2: bilinear interp from s_win + main GEMM (wdT2 global).
//   - barrier; epilogue via s_out overlay of s_win; barrier; store.
//  LDS 35584 B -> 4 blocks/CU (16 waves/CU); 3 barriers; no vmcnt asm.
// ---------------------------------------------------------------------------
__global__ __launch_bounds__(256, 3) void mega_kernel(const ushort* __restrict__ xt,
                                                      const ushort* __restrict__ ft,
                                                      const ushort* __restrict__ wdT2,
                                                      const ushort* __restrict__ woT2,
                                                      const float* __restrict__ b_off,
                                                      const float* __restrict__ b_def,
                                                      float* __restrict__ out) {
    __shared__ __align__(16) char smem[35584];
    ushort* s_win = (ushort*)smem;             // xt window: 224 lins * 128 B
    float* s_om = (float*)(smem + 28672);      // [27][64] f32 (6912 B)
    float* s_out = (float*)smem;               // [64][68] f32 overlay of s_win

    int t = threadIdx.x;
    int wv = t >> 6, l = t & 63;
    int q = l >> 4, r = l & 15;
    int blk = (blockIdx.x & 7) * 128 + (blockIdx.x >> 3);  // XCD band swizzle
    int b = blk >> 8;
    int gi = blk & 255;
    int h = (gi >> 2) << 1;           // even row; block covers rows h, h+1
    int wbase = (gi & 3) << 5;        // 32-col strip
    int rowoff = wv >> 1, pxh = wv & 1;
    int hrow = h + rowoff;
    int pxi = pxh * 16 + r;           // col within strip [0,32)
    float pxif = (float)pxi;
    float rowofff = (float)rowoff;
    const ushort* xt_b = xt + (size_t)b * HWn * Cn;
    const ushort* ft_b = ft + (size_t)b * HWn * Cn;

    // ---- (a) DMA xt window (rows h-2..h+3, cols wbase-2..wbase+33) ----
#pragma unroll
    for (int i = 0; i < 7; ++i) {
        int jb = i * 256 + wv * 64;
        int j = jb + l;
        int lin = j >> 3, slot = j & 7;
        int linc = min(lin, 215);
        int cidx = (slot - lin) & 7;  // inverse of read rotation
        int row = linc / 36, col = linc - row * 36;
        int rs = min(max(h - 2 + row, 0), Hn - 1);
        int cs = min(max(wbase - 2 + col, 0), Wn - 1);
        const ushort* gp = xt_b + (size_t)(rs * Wn + cs) * Cn + cidx * 8;
        __builtin_amdgcn_global_load_lds(
            (const __attribute__((address_space(1))) unsigned int*)gp,
            (__attribute__((address_space(3))) unsigned int*)(s_win + (size_t)jb * 8),
            16, 0, 0);
    }

    f32x4 zero = {0.f, 0.f, 0.f, 0.f};
    s16x8 zz = {0, 0, 0, 0, 0, 0, 0, 0};

    // ---- phase 1: om GEMM, ft direct from global (L1/L2-hot) ----
    f32x4 acc2[2];
    acc2[0] = zero; acc2[1] = zero;
    {
        int pxg = wv * 16 + r;            // GEMM M-index (block-local px)
        int rg = pxg >> 5, cg = pxg & 31;
#pragma unroll 3
        for (int k = 0; k < 9; ++k) {
            int dy = k / 3 - 1, dx = k % 3 - 1;
            int y = h + rg + dy;
            bool yv = (y >= 0) && (y < Hn);
            int xx = wbase + cg + dx;
            bool valid = yv && (xx >= 0) && (xx < Wn);
            int ys_ = min(max(y, 0), Hn - 1);
            int xs_ = min(max(xx, 0), Wn - 1);
            const ushort* ap = ft_b + (size_t)(ys_ * Wn + xs_) * Cn;
#pragma unroll
            for (int s = 0; s < 2; ++s) {
                s16x8 av = *(const s16x8*)(ap + (s * 4 + q) * 8);
                av = valid ? av : zz;
#pragma unroll
                for (int ot = 0; ot < 2; ++ot) {
                    s16x8 bv = *(const s16x8*)(woT2 + (size_t)s * 9216
                                               + (size_t)(k * 32 + ot * 16 + r) * 32 + q * 8);
                    acc2[ot] = __builtin_amdgcn_mfma_f32_16x16x32_bf16(av, bv, acc2[ot], 0, 0, 0);
                }
            }
        }
    }

    // ---- bounce: bias + sigmoid -> s_om[27][64] ----
#pragma unroll
    for (int ot = 0; ot < 2; ++ot) {
        int oc = ot * 16 + r;
        if (oc < 27) {
            float bo = b_off[oc];
#pragma unroll
            for (int reg = 0; reg < 4; ++reg) {
                int p = wv * 16 + q * 4 + reg;
                float v = acc2[ot][reg] + bo;
                if (oc >= 18) v = 1.f / (1.f + __expf(-v));
                s_om[oc * 64 + p] = v;
            }
        }
    }
    __syncthreads();  // (1) s_om visible; drains xt DMA (vmcnt 0)

    // ---- per-lane om values + vote ----
    float omv[27];
#pragma unroll
    for (int o = 0; o < 27; ++o) omv[o] = s_om[o * 64 + rowoff * 32 + pxi];
    bool okp = true;
#pragma unroll
    for (int k = 0; k < 9; ++k) {
        float uy = (float)(k / 3 - 1) + omv[9 + k];
        float ux = pxif + (float)(k % 3 - 1) + omv[k];
        okp = okp && (uy >= -2.f - rowofff) && (uy < 3.f - rowofff)
                  && (ux >= -2.f) && (ux < 33.f);
    }
    int fast = __all(okp) ? 1 : 0;

    f32x4 acc[4];
    acc[0] = zero; acc[1] = zero; acc[2] = zero; acc[3] = zero;

    if (fast) {
#pragma unroll 3
        for (int k = 0; k < 9; ++k) {
            float uy = (float)(k / 3 - 1) + omv[9 + k];
            float ux = pxif + (float)(k % 3 - 1) + omv[k];
            float mv = omv[18 + k];
            float y0f = floorf(uy), x0f = floorf(ux);
            float fy = uy - y0f, fx = ux - x0f;
            int iy = (int)y0f + 2 + rowoff;  // 0..4
            int ix = (int)x0f + 2;           // 0..34
            int yab = hrow + (int)y0f, xab = wbase + (int)x0f;
            bool vy0 = (yab >= 0) && (yab < Hn);
            bool vy1 = (yab + 1 >= 0) && (yab + 1 < Hn);
            bool vx0 = (xab >= 0) && (xab < Wn);
            bool vx1 = (xab + 1 >= 0) && (xab + 1 < Wn);
            float g0 = (vy0 && vx0) ? (1.f - fy) * (1.f - fx) * mv : 0.f;
            float g1 = (vy0 && vx1) ? (1.f - fy) * fx * mv : 0.f;
            float g2 = (vy1 && vx0) ? fy * (1.f - fx) * mv : 0.f;
            float g3 = (vy1 && vx1) ? fy * fx * mv : 0.f;
            int l0 = iy * 36 + ix, l1 = l0 + 1, l2 = l0 + 36, l3 = l0 + 37;
            // weights for this tap (global, L2-hot): full 64 oc
            s16x8 bw[2][4];
#pragma unroll
            for (int s = 0; s < 2; ++s)
#pragma unroll
                for (int ot = 0; ot < 4; ++ot)
                    bw[s][ot] = *(const s16x8*)(wdT2 + (size_t)s * 18432
                                                + (size_t)(k * 64 + ot * 16 + r) * 32 + q * 8);
            s16x8 af[2];
#pragma unroll
            for (int s = 0; s < 2; ++s) {
                int c = s * 4 + q;  // logical chunk
                s16x8 q0 = *(const s16x8*)&s_win[l0 * 64 + (((c + l0) & 7) << 3)];
                s16x8 q1 = *(const s16x8*)&s_win[l1 * 64 + (((c + l1) & 7) << 3)];
                s16x8 q2 = *(const s16x8*)&s_win[l2 * 64 + (((c + l2) & 7) << 3)];
                s16x8 q3 = *(const s16x8*)&s_win[l3 * 64 + (((c + l3) & 7) << 3)];
                s16x8 p;
#pragma unroll
                for (int j = 0; j < 8; ++j) {
                    float rr = g0 * bf2f((unsigned short)q0[j]) + g1 * bf2f((unsigned short)q1[j])
                             + g2 * bf2f((unsigned short)q2[j]) + g3 * bf2f((unsigned short)q3[j]);
                    p[j] = (short)f2bf(rr);
                }
                af[s] = p;
            }
#pragma unroll
            for (int s = 0; s < 2; ++s)
#pragma unroll
                for (int ot = 0; ot < 4; ++ot)
                    acc[ot] = __builtin_amdgcn_mfma_f32_16x16x32_bf16(af[s], bw[s][ot], acc[ot], 0, 0, 0);
        }
    } else {
        // slow path (rare, any-input correct): global gathers + global weights
#pragma unroll 1
        for (int k = 0; k < 9; ++k) {
            float ys = (float)(hrow + k / 3 - 1) + omv[9 + k];
            float xs = (float)(wbase + pxi + k % 3 - 1) + omv[k];
            float mv = omv[18 + k];
            float y0f = floorf(ys), x0f = floorf(xs);
            float fy = ys - y0f, fx = xs - x0f;
            int y0 = (int)y0f, x0 = (int)x0f;
            float g[4];
            int a[4];
#pragma unroll
            for (int n = 0; n < 4; ++n) {
                int yy = y0 + (n >> 1), xx = x0 + (n & 1);
                bool valid = (yy >= 0) && (yy < Hn) && (xx >= 0) && (xx < Wn);
                float wgt = ((n >> 1) ? fy : 1.f - fy) * ((n & 1) ? fx : 1.f - fx) * mv;
                g[n] = valid ? wgt : 0.f;
                int yc = min(max(yy, 0), Hn - 1), xc = min(max(xx, 0), Wn - 1);
                a[n] = (yc * Wn + xc) * Cn;
            }
#pragma unroll
            for (int s = 0; s < 2; ++s) {
                int c = s * 32 + q * 8;
                s16x8 q0 = *(const s16x8*)(xt_b + a[0] + c);
                s16x8 q1 = *(const s16x8*)(xt_b + a[1] + c);
                s16x8 q2 = *(const s16x8*)(xt_b + a[2] + c);
                s16x8 q3 = *(const s16x8*)(xt_b + a[3] + c);
                s16x8 af;
#pragma unroll
                for (int j = 0; j < 8; ++j) {
                    float rr = g[0] * bf2f((unsigned short)q0[j]) + g[1] * bf2f((unsigned short)q1[j])
                             + g[2] * bf2f((unsigned short)q2[j]) + g[3] * bf2f((unsigned short)q3[j]);
                    af[j] = (short)f2bf(rr);
                }
#pragma unroll
                for (int ot = 0; ot < 4; ++ot) {
                    s16x8 bv = *(const s16x8*)(wdT2 + (size_t)s * 18432
                                               + (size_t)(k * 64 + ot * 16 + r) * 32 + q * 8);
                    acc[ot] = __builtin_amdgcn_mfma_f32_16x16x32_bf16(af, bv, acc[ot], 0, 0, 0);
                }
            }
        }
    }
    __syncthreads();  // (2) all s_win reads done; region becomes s_out

    // ---- epilogue: bias + ReLU, stage [oc][px64], coalesced store ----
#pragma unroll
    for (int ot = 0; ot < 4; ++ot) {
        int oc = ot * 16 + r;
        float bv = b_def[oc];
        f32x4 vv;
#pragma unroll
        for (int reg = 0; reg < 4; ++reg) vv[reg] = fmaxf(acc[ot][reg] + bv, 0.f);
        *(f32x4*)&s_out[oc * 68 + rowoff * 32 + pxh * 16 + q * 4] = vv;
    }
    __syncthreads();  // (3)
    {
        int px = t & 63, og = t >> 6;
        int rg = h + (px >> 5);
        float* ob = out + ((size_t)b * On) * HWn + rg * Wn + wbase + (px & 31);
#pragma unroll
        for (int j = 0; j < 16; ++j) {
            int oc = og * 16 + j;
            ob[(size_t)oc * HWn] = s_out[oc * 68 + px];
        }
    }
}

// ---------------------------------------------------------------------------
extern "C" void kernel_launch(void* const* d_in, const int* in_sizes, int n_in,
                              void* d_out, int out_size, void* d_ws, size_t ws_size,
                              hipStream_t stream) {
    const float* x = (const float*)d_in[0];
    const float* feat = (const float*)d_in[1];
    const float* w_off = (const float*)d_in[2];
    const float* b_off = (const float*)d_in[3];
    const float* w_def = (const float*)d_in[4];
    const float* b_def = (const float*)d_in[5];
    float* out = (float*)d_out;

    char* ws = (char*)d_ws;
    ushort* xt = (ushort*)ws;                           // 8 MB [B,HW,C] bf16
    ushort* ft = (ushort*)(ws + 8388608);               // 8 MB [B,HW,C] bf16
    ushort* wdT2 = (ushort*)(ws + 16777216);            // 73728 B [2][9][64][32]
    ushort* woT2 = (ushort*)(ws + 16850944);            // 36864 B [2][9][32][32]

    hipLaunchKernelGGL(transpose_all, dim3(HWn / 64, Bn, 3), dim3(256), 0, stream,
                       x, feat, w_def, w_off, xt, ft, wdT2, woT2);
    hipLaunchKernelGGL(mega_kernel, dim3((Bn * HWn) / 64), dim3(256), 0, stream,
                       xt, ft, wdT2, woT2, b_off, b_def, out);
}

// Round 9
// 124.732 us; speedup vs baseline: 1.3477x; 1.0279x over previous
//
#include <hip/hip_runtime.h>
#include <math.h>

#define Bn 4
#define Cn 64
#define On 64
#define Hn 128
#define Wn 128
#define HWn (Hn * Wn)

typedef __attribute__((ext_vector_type(8))) short s16x8;
typedef __attribute__((ext_vector_type(4))) float f32x4;

__device__ __forceinline__ unsigned short f2bf(float f) {
    unsigned u = __float_as_uint(f);
    u += 0x7fffu + ((u >> 16) & 1u);  // RTNE (finite values)
    return (unsigned short)(u >> 16);
}
__device__ __forceinline__ float bf2f(unsigned short u) {
    return __uint_as_float(((unsigned)u) << 16);
}

// ---------------------------------------------------------------------------
// K1: z=0: x -> xt [B,HW,C] bf16; z=1: feat -> ft; z=2: weights ->
//   wdT2 [2s][9k][64oc][32c] bf16, woT2 [2s][9k][32oc][32c] bf16 (oc>=27 -> 0)
// ---------------------------------------------------------------------------
__global__ __launch_bounds__(256) void transpose_all(const float* __restrict__ x,
                                                     const float* __restrict__ feat,
                                                     const float* __restrict__ wdef,
                                                     const float* __restrict__ woff,
                                                     ushort* __restrict__ xt,
                                                     ushort* __restrict__ ft,
                                                     ushort* __restrict__ wdT2,
                                                     ushort* __restrict__ woT2) {
    int t = threadIdx.x;
    if (blockIdx.z == 2) {
        int id = (blockIdx.y * gridDim.x + blockIdx.x) * 256 + t;
        if (id < 36864) {  // [s][k][oc 64][c 32]
            int c2 = id & 31, oc = (id >> 5) & 63, ks = id >> 11;
            int k = ks % 9, s = ks / 9;
            wdT2[id] = f2bf(wdef[(oc * 64 + s * 32 + c2) * 9 + k]);
        } else if (id < 55296) {  // [s][k][oc 32][c 32]
            int i2 = id - 36864;
            int c2 = i2 & 31, oc = (i2 >> 5) & 31, ks = i2 >> 10;
            int k = ks % 9, s = ks / 9;
            woT2[i2] = (oc < 27) ? f2bf(woff[(oc * 64 + s * 32 + c2) * 9 + k]) : (ushort)0;
        }
        return;
    }
    __shared__ float tile[64][65];
    const float* src = blockIdx.z ? feat : x;
    ushort* dst0 = blockIdx.z ? ft : xt;
    int b = blockIdx.y, hw0 = blockIdx.x * 64;
    int lane = t & 63, grp = t >> 6;
    const float* xb = src + (size_t)b * Cn * HWn;
#pragma unroll
    for (int i = 0; i < 16; ++i) {
        int c = grp * 16 + i;
        tile[lane][c] = xb[(size_t)c * HWn + hw0 + lane];  // coalesced along hw
    }
    __syncthreads();
#pragma unroll
    for (int jj = 0; jj < 2; ++jj) {
        int px = jj * 32 + (t >> 3), ch = t & 7;
        s16x8 p;
#pragma unroll
        for (int j = 0; j < 8; ++j) p[j] = (short)f2bf(tile[px][ch * 8 + j]);
        *(s16x8*)(dst0 + ((size_t)(b * HWn + hw0 + px)) * Cn + ch * 8) = p;  // coalesced
    }
}

// ---------------------------------------------------------------------------
// K2 (fused): R19 = R15 (verified best) + direct epilogue stores.
//  R16/R17/R18 isolations: xt gathers need LDS (R16 −56 µs proof); ft needs
//  staging too (R18: direct ft = +5 µs); cvt_pk asm is poison (m240).
//  Per block (2 rows x 32 cols, 4 waves):
//   - DMA ft window FIRST (4x36, 144 lins), xt window LAST (6x36, 216 pad
//     224). vmcnt(7) + raw s_barrier: ft ready (per-wave ft issues 5/5/4/4,
//     xt uniformly 7 -> vmcnt(7) drains all ft), xt stays in flight under
//     ALL of phase 1 (T14).
//   - phase 1: om GEMM from s_ft, weights global woT2 (L2-hot);
//     bias+sigmoid -> s_om overlay of dead ft region.
//   - barrier; 27 om LDS reads; vote; phase 2: bilinear interp from s_win
//     + main GEMM (wdT2 global).
//   - NEW: epilogue stores acc DIRECTLY to global (aligned f32x4, 4 px per
//     store; block's pieces share two 128-B lines per oc-row -> L2 write-
//     combines, WRITE_SIZE unchanged). Removes s_out bounce + 2 barriers.
//  LDS 47104 B (3 blocks/CU); 3 barriers (was 5).
// ---------------------------------------------------------------------------
__global__ __launch_bounds__(256, 3) void mega_kernel(const ushort* __restrict__ xt,
                                                      const ushort* __restrict__ ft,
                                                      const ushort* __restrict__ wdT2,
                                                      const ushort* __restrict__ woT2,
                                                      const float* __restrict__ b_off,
                                                      const float* __restrict__ b_def,
                                                      float* __restrict__ out) {
    __shared__ __align__(16) char smem[47104];
    ushort* s_win = (ushort*)smem;             // xt window: 224 lins * 128 B
    ushort* s_ft = (ushort*)(smem + 28672);    // ft window: 144 lins * 128 B
    float* s_om = (float*)(smem + 28672);      // [27][64] f32 overlay (6912 B)

    int t = threadIdx.x;
    int wv = t >> 6, l = t & 63;
    int q = l >> 4, r = l & 15;
    int blk = (blockIdx.x & 7) * 128 + (blockIdx.x >> 3);  // XCD band swizzle
    int b = blk >> 8;
    int gi = blk & 255;
    int h = (gi >> 2) << 1;           // even row; block covers rows h, h+1
    int wbase = (gi & 3) << 5;        // 32-col strip
    int rowoff = wv >> 1, pxh = wv & 1;
    int hrow = h + rowoff;
    int pxi = pxh * 16 + r;           // col within strip [0,32)
    float pxif = (float)pxi;
    float rowofff = (float)rowoff;
    const ushort* xt_b = xt + (size_t)b * HWn * Cn;
    const ushort* ft_b = ft + (size_t)b * HWn * Cn;

    // ---- (a) DMA ft window FIRST (rows h-1..h+2, cols wbase-2..wbase+33) --
#pragma unroll
    for (int i = 0; i < 5; ++i) {
        int jb = i * 256 + wv * 64;  // wave-uniform
        if (jb < 1152) {             // 144 lins x 8 chunks
            int j = jb + l;
            int lin = j >> 3, slot = j & 7;
            int cidx = (slot - lin) & 7;  // inverse of read rotation
            int row = lin / 36, col = lin - row * 36;
            int rs = min(max(h - 1 + row, 0), Hn - 1);
            int cs = min(max(wbase - 2 + col, 0), Wn - 1);
            const ushort* gp = ft_b + (size_t)(rs * Wn + cs) * Cn + cidx * 8;
            __builtin_amdgcn_global_load_lds(
                (const __attribute__((address_space(1))) unsigned int*)gp,
                (__attribute__((address_space(3))) unsigned int*)(s_ft + (size_t)jb * 8),
                16, 0, 0);
        }
    }
    // ---- (b) DMA xt window LAST (rows h-2..h+3, cols wbase-2..wbase+33) --
#pragma unroll
    for (int i = 0; i < 7; ++i) {
        int jb = i * 256 + wv * 64;
        int j = jb + l;
        int lin = j >> 3, slot = j & 7;
        int linc = min(lin, 215);
        int cidx = (slot - lin) & 7;
        int row = linc / 36, col = linc - row * 36;
        int rs = min(max(h - 2 + row, 0), Hn - 1);
        int cs = min(max(wbase - 2 + col, 0), Wn - 1);
        const ushort* gp = xt_b + (size_t)(rs * Wn + cs) * Cn + cidx * 8;
        __builtin_amdgcn_global_load_lds(
            (const __attribute__((address_space(1))) unsigned int*)gp,
            (__attribute__((address_space(3))) unsigned int*)(s_win + (size_t)jb * 8),
            16, 0, 0);
    }
    // ft complete (its DMAs are oldest); xt's 7 remain in flight
    asm volatile("s_waitcnt vmcnt(7)" ::: "memory");
    __builtin_amdgcn_s_barrier();  // (1) ft window ready for all waves

    f32x4 zero = {0.f, 0.f, 0.f, 0.f};
    s16x8 zz = {0, 0, 0, 0, 0, 0, 0, 0};

    // ---- phase 1: om GEMM from ft window ----
    f32x4 acc2[2];
    acc2[0] = zero; acc2[1] = zero;
    {
        int pxg = wv * 16 + r;            // GEMM M-index (block-local px)
        int rg = pxg >> 5, cg = pxg & 31;
#pragma unroll 3
        for (int k = 0; k < 9; ++k) {
            int dy = k / 3 - 1, dx = k % 3 - 1;
            int y = h + rg + dy;
            bool yv = (y >= 0) && (y < Hn);
            int xx = wbase + cg + dx;
            bool valid = yv && (xx >= 0) && (xx < Wn);
            int lin = (rg + dy + 1) * 36 + cg + dx + 2;
#pragma unroll
            for (int s = 0; s < 2; ++s) {
                int c = s * 4 + q;
                s16x8 av = *(const s16x8*)&s_ft[lin * 64 + (((c + lin) & 7) << 3)];
                av = valid ? av : zz;
#pragma unroll
                for (int ot = 0; ot < 2; ++ot) {
                    s16x8 bv = *(const s16x8*)(woT2 + (size_t)s * 9216
                                               + (size_t)(k * 32 + ot * 16 + r) * 32 + q * 8);
                    acc2[ot] = __builtin_amdgcn_mfma_f32_16x16x32_bf16(av, bv, acc2[ot], 0, 0, 0);
                }
            }
        }
    }
    __syncthreads();  // (2) ft reads done; region becomes s_om

    // ---- bounce: bias + sigmoid -> s_om[27][64] ----
#pragma unroll
    for (int ot = 0; ot < 2; ++ot) {
        int oc = ot * 16 + r;
        if (oc < 27) {
            float bo = b_off[oc];
#pragma unroll
            for (int reg = 0; reg < 4; ++reg) {
                int p = wv * 16 + q * 4 + reg;
                float v = acc2[ot][reg] + bo;
                if (oc >= 18) v = 1.f / (1.f + __expf(-v));
                s_om[oc * 64 + p] = v;
            }
        }
    }
    __syncthreads();  // (3) s_om visible; drains xt DMA (vmcnt 0)

    // ---- per-lane om values + vote ----
    float omv[27];
#pragma unroll
    for (int o = 0; o < 27; ++o) omv[o] = s_om[o * 64 + rowoff * 32 + pxi];
    bool okp = true;
#pragma unroll
    for (int k = 0; k < 9; ++k) {
        float uy = (float)(k / 3 - 1) + omv[9 + k];
        float ux = pxif + (float)(k % 3 - 1) + omv[k];
        okp = okp && (uy >= -2.f - rowofff) && (uy < 3.f - rowofff)
                  && (ux >= -2.f) && (ux < 33.f);
    }
    int fast = __all(okp) ? 1 : 0;

    f32x4 acc[4];
    acc[0] = zero; acc[1] = zero; acc[2] = zero; acc[3] = zero;

    if (fast) {
#pragma unroll 3
        for (int k = 0; k < 9; ++k) {
            float uy = (float)(k / 3 - 1) + omv[9 + k];
            float ux = pxif + (float)(k % 3 - 1) + omv[k];
            float mv = omv[18 + k];
            float y0f = floorf(uy), x0f = floorf(ux);
            float fy = uy - y0f, fx = ux - x0f;
            int iy = (int)y0f + 2 + rowoff;  // 0..4
            int ix = (int)x0f + 2;           // 0..34
            int yab = hrow + (int)y0f, xab = wbase + (int)x0f;
            bool vy0 = (yab >= 0) && (yab < Hn);
            bool vy1 = (yab + 1 >= 0) && (yab + 1 < Hn);
            bool vx0 = (xab >= 0) && (xab < Wn);
            bool vx1 = (xab + 1 >= 0) && (xab + 1 < Wn);
            float g0 = (vy0 && vx0) ? (1.f - fy) * (1.f - fx) * mv : 0.f;
            float g1 = (vy0 && vx1) ? (1.f - fy) * fx * mv : 0.f;
            float g2 = (vy1 && vx0) ? fy * (1.f - fx) * mv : 0.f;
            float g3 = (vy1 && vx1) ? fy * fx * mv : 0.f;
            int l0 = iy * 36 + ix, l1 = l0 + 1, l2 = l0 + 36, l3 = l0 + 37;
            // weights for this tap (global, L2-hot): full 64 oc
            s16x8 bw[2][4];
#pragma unroll
            for (int s = 0; s < 2; ++s)
#pragma unroll
                for (int ot = 0; ot < 4; ++ot)
                    bw[s][ot] = *(const s16x8*)(wdT2 + (size_t)s * 18432
                                                + (size_t)(k * 64 + ot * 16 + r) * 32 + q * 8);
            s16x8 af[2];
#pragma unroll
            for (int s = 0; s < 2; ++s) {
                int c = s * 4 + q;  // logical chunk
                s16x8 q0 = *(const s16x8*)&s_win[l0 * 64 + (((c + l0) & 7) << 3)];
                s16x8 q1 = *(const s16x8*)&s_win[l1 * 64 + (((c + l1) & 7) << 3)];
                s16x8 q2 = *(const s16x8*)&s_win[l2 * 64 + (((c + l2) & 7) << 3)];
                s16x8 q3 = *(const s16x8*)&s_win[l3 * 64 + (((c + l3) & 7) << 3)];
                s16x8 p;
#pragma unroll
                for (int j = 0; j < 8; ++j) {
                    float rr = g0 * bf2f((unsigned short)q0[j]) + g1 * bf2f((unsigned short)q1[j])
                             + g2 * bf2f((unsigned short)q2[j]) + g3 * bf2f((unsigned short)q3[j]);
                    p[j] = (short)f2bf(rr);
                }
                af[s] = p;
            }
#pragma unroll
            for (int s = 0; s < 2; ++s)
#pragma unroll
                for (int ot = 0; ot < 4; ++ot)
                    acc[ot] = __builtin_amdgcn_mfma_f32_16x16x32_bf16(af[s], bw[s][ot], acc[ot], 0, 0, 0);
        }
    } else {
        // slow path (rare, any-input correct): global gathers + global weights
#pragma unroll 1
        for (int k = 0; k < 9; ++k) {
            float ys = (float)(hrow + k / 3 - 1) + omv[9 + k];
            float xs = (float)(wbase + pxi + k % 3 - 1) + omv[k];
            float mv = omv[18 + k];
            float y0f = floorf(ys), x0f = floorf(xs);
            float fy = ys - y0f, fx = xs - x0f;
            int y0 = (int)y0f, x0 = (int)x0f;
            float g[4];
            int a[4];
#pragma unroll
            for (int n = 0; n < 4; ++n) {
                int yy = y0 + (n >> 1), xx = x0 + (n & 1);
                bool valid = (yy >= 0) && (yy < Hn) && (xx >= 0) && (xx < Wn);
                float wgt = ((n >> 1) ? fy : 1.f - fy) * ((n & 1) ? fx : 1.f - fx) * mv;
                g[n] = valid ? wgt : 0.f;
                int yc = min(max(yy, 0), Hn - 1), xc = min(max(xx, 0), Wn - 1);
                a[n] = (yc * Wn + xc) * Cn;
            }
#pragma unroll
            for (int s = 0; s < 2; ++s) {
                int c = s * 32 + q * 8;
                s16x8 q0 = *(const s16x8*)(xt_b + a[0] + c);
                s16x8 q1 = *(const s16x8*)(xt_b + a[1] + c);
                s16x8 q2 = *(const s16x8*)(xt_b + a[2] + c);
                s16x8 q3 = *(const s16x8*)(xt_b + a[3] + c);
                s16x8 af;
#pragma unroll
                for (int j = 0; j < 8; ++j) {
                    float rr = g[0] * bf2f((unsigned short)q0[j]) + g[1] * bf2f((unsigned short)q1[j])
                             + g[2] * bf2f((unsigned short)q2[j]) + g[3] * bf2f((unsigned short)q3[j]);
                    af[j] = (short)f2bf(rr);
                }
#pragma unroll
                for (int ot = 0; ot < 4; ++ot) {
                    s16x8 bv = *(const s16x8*)(wdT2 + (size_t)s * 18432
                                               + (size_t)(k * 64 + ot * 16 + r) * 32 + q * 8);
                    acc[ot] = __builtin_amdgcn_mfma_f32_16x16x32_bf16(af, bv, acc[ot], 0, 0, 0);
                }
            }
        }
    }

    // ---- epilogue: bias + ReLU, DIRECT aligned f32x4 stores (no LDS
    //      bounce, no barriers): acc[ot][reg] -> out[b][ot*16+r][hrow]
    //      [wbase + pxh*16 + q*4 + reg]; L2 write-combines the 16-B pieces.
    {
        float* ob = out + (size_t)b * On * HWn + (size_t)hrow * Wn + wbase + pxh * 16 + q * 4;
#pragma unroll
        for (int ot = 0; ot < 4; ++ot) {
            int oc = ot * 16 + r;
            float bv = b_def[oc];
            f32x4 vv;
#pragma unroll
            for (int reg = 0; reg < 4; ++reg) vv[reg] = fmaxf(acc[ot][reg] + bv, 0.f);
            *(f32x4*)(ob + (size_t)oc * HWn) = vv;
        }
    }
}

// ---------------------------------------------------------------------------
extern "C" void kernel_launch(void* const* d_in, const int* in_sizes, int n_in,
                              void* d_out, int out_size, void* d_ws, size_t ws_size,
                              hipStream_t stream) {
    const float* x = (const float*)d_in[0];
    const float* feat = (const float*)d_in[1];
    const float* w_off = (const float*)d_in[2];
    const float* b_off = (const float*)d_in[3];
    const float* w_def = (const float*)d_in[4];
    const float* b_def = (const float*)d_in[5];
    float* out = (float*)d_out;

    char* ws = (char*)d_ws;
    ushort* xt = (ushort*)ws;                           // 8 MB [B,HW,C] bf16
    ushort* ft = (ushort*)(ws + 8388608);               // 8 MB [B,HW,C] bf16
    ushort* wdT2 = (ushort*)(ws + 16777216);            // 73728 B [2][9][64][32]
    ushort* woT2 = (ushort*)(ws + 16850944);            // 36864 B [2][9][32][32]

    hipLaunchKernelGGL(transpose_all, dim3(HWn / 64, Bn, 3), dim3(256), 0, stream,
                       x, feat, w_def, w_off, xt, ft, wdT2, woT2);
    hipLaunchKernelGGL(mega_kernel, dim3((Bn * HWn) / 64), dim3(256), 0, stream,
                       xt, ft, wdT2, woT2, b_off, b_def, out);
}

// Round 10
// 123.212 us; speedup vs baseline: 1.3644x; 1.0123x over previous
//
#include <hip/hip_runtime.h>
#include <math.h>

#define Bn 4
#define Cn 64
#define On 64
#define Hn 128
#define Wn 128
#define HWn (Hn * Wn)

typedef __attribute__((ext_vector_type(8))) short s16x8;
typedef __attribute__((ext_vector_type(4))) float f32x4;

__device__ __forceinline__ unsigned short f2bf(float f) {
    unsigned u = __float_as_uint(f);
    u += 0x7fffu + ((u >> 16) & 1u);  // RTNE (finite values)
    return (unsigned short)(u >> 16);
}
__device__ __forceinline__ float bf2f(unsigned short u) {
    return __uint_as_float(((unsigned)u) << 16);
}

// ---------------------------------------------------------------------------
// K1: z=0: x -> xt [B,HW,C] bf16; z=1: feat -> ft; z=2: weights ->
//   wdT2 [2s][9k][64oc][32c] bf16, woT2 [2s][9k][32oc][32c] bf16 (oc>=27 -> 0)
// ---------------------------------------------------------------------------
__global__ __launch_bounds__(256) void transpose_all(const float* __restrict__ x,
                                                     const float* __restrict__ feat,
                                                     const float* __restrict__ wdef,
                                                     const float* __restrict__ woff,
                                                     ushort* __restrict__ xt,
                                                     ushort* __restrict__ ft,
                                                     ushort* __restrict__ wdT2,
                                                     ushort* __restrict__ woT2) {
    int t = threadIdx.x;
    if (blockIdx.z == 2) {
        int id = (blockIdx.y * gridDim.x + blockIdx.x) * 256 + t;
        if (id < 36864) {  // [s][k][oc 64][c 32]
            int c2 = id & 31, oc = (id >> 5) & 63, ks = id >> 11;
            int k = ks % 9, s = ks / 9;
            wdT2[id] = f2bf(wdef[(oc * 64 + s * 32 + c2) * 9 + k]);
        } else if (id < 55296) {  // [s][k][oc 32][c 32]
            int i2 = id - 36864;
            int c2 = i2 & 31, oc = (i2 >> 5) & 31, ks = i2 >> 10;
            int k = ks % 9, s = ks / 9;
            woT2[i2] = (oc < 27) ? f2bf(woff[(oc * 64 + s * 32 + c2) * 9 + k]) : (ushort)0;
        }
        return;
    }
    __shared__ float tile[64][65];
    const float* src = blockIdx.z ? feat : x;
    ushort* dst0 = blockIdx.z ? ft : xt;
    int b = blockIdx.y, hw0 = blockIdx.x * 64;
    int lane = t & 63, grp = t >> 6;
    const float* xb = src + (size_t)b * Cn * HWn;
#pragma unroll
    for (int i = 0; i < 16; ++i) {
        int c = grp * 16 + i;
        tile[lane][c] = xb[(size_t)c * HWn + hw0 + lane];  // coalesced along hw
    }
    __syncthreads();
#pragma unroll
    for (int jj = 0; jj < 2; ++jj) {
        int px = jj * 32 + (t >> 3), ch = t & 7;
        s16x8 p;
#pragma unroll
        for (int j = 0; j < 8; ++j) p[j] = (short)f2bf(tile[px][ch * 8 + j]);
        *(s16x8*)(dst0 + ((size_t)(b * HWn + hw0 + px)) * Cn + ch * 8) = p;  // coalesced
    }
}

// ---------------------------------------------------------------------------
// K2 (fused): R20 = R19 schedule scaled to 4-row blocks (128 px, 512 thr,
//  8 waves). Same per-wave tile (16 px x 64 oc), same rotation layouts,
//  same 3-barrier T14 schedule, direct epilogue stores (R19-neutral,
//  WRITE_SIZE-verified). Changes:
//   - xt window rows h-2..h+5 (8x36 = 288 lins, 36864 B): 2.0 staged rows
//     per output row (was 3.0); ft rows h-1..h+4 (6x36 = 216 lins, 27648 B,
//     1728 = 27x64 chunks exactly): 1.5 (was 2.0). Staging bytes/px -33%.
//   - LDS 64512 B -> 2 blocks/CU x 8 waves = 16 waves/CU (was 12).
//   - vmcnt(4): per-wave ft issues 4/4/4/3/3/3/3/3, xt 5/5/5/5/4/4/4/4 ->
//     vmcnt(4) drains every wave's ft; xt stays in flight under phase 1.
//   - vote rows widen: uy in [-2-rowoff, 5-rowoff); iy in [0,6], +1 -> 7.
//   - s_om [27][128] f32 (13824 B) overlays dead ft region.
// ---------------------------------------------------------------------------
__global__ __launch_bounds__(512, 2) void mega_kernel(const ushort* __restrict__ xt,
                                                      const ushort* __restrict__ ft,
                                                      const ushort* __restrict__ wdT2,
                                                      const ushort* __restrict__ woT2,
                                                      const float* __restrict__ b_off,
                                                      const float* __restrict__ b_def,
                                                      float* __restrict__ out) {
    __shared__ __align__(16) char smem[64512];
    ushort* s_win = (ushort*)smem;             // xt window: 288 lins * 128 B
    ushort* s_ft = (ushort*)(smem + 36864);    // ft window: 216 lins * 128 B
    float* s_om = (float*)(smem + 36864);      // [27][128] f32 overlay (13824 B)

    int t = threadIdx.x;
    int wv = t >> 6, l = t & 63;
    int q = l >> 4, r = l & 15;
    int blk = (blockIdx.x & 7) * 64 + (blockIdx.x >> 3);  // XCD band swizzle (512=8x64)
    int b = blk >> 7;                 // 128 blocks per batch
    int gi = blk & 127;
    int h = (gi >> 2) << 2;           // block covers rows h..h+3
    int wbase = (gi & 3) << 5;        // 32-col strip
    int rowoff = wv >> 1, pxh = wv & 1;
    int hrow = h + rowoff;
    int pxi = pxh * 16 + r;           // col within strip [0,32)
    float pxif = (float)pxi;
    float rowofff = (float)rowoff;
    const ushort* xt_b = xt + (size_t)b * HWn * Cn;
    const ushort* ft_b = ft + (size_t)b * HWn * Cn;

    // ---- (a) DMA ft window FIRST (rows h-1..h+4, cols wbase-2..wbase+33) --
#pragma unroll
    for (int i = 0; i < 4; ++i) {
        int jb = i * 512 + wv * 64;  // wave-uniform
        if (jb < 1728) {             // 216 lins x 8 chunks
            int j = jb + l;
            int lin = j >> 3, slot = j & 7;
            int cidx = (slot - lin) & 7;  // inverse of read rotation
            int row = lin / 36, col = lin - row * 36;
            int rs = min(max(h - 1 + row, 0), Hn - 1);
            int cs = min(max(wbase - 2 + col, 0), Wn - 1);
            const ushort* gp = ft_b + (size_t)(rs * Wn + cs) * Cn + cidx * 8;
            __builtin_amdgcn_global_load_lds(
                (const __attribute__((address_space(1))) unsigned int*)gp,
                (__attribute__((address_space(3))) unsigned int*)(s_ft + (size_t)jb * 8),
                16, 0, 0);
        }
    }
    // ---- (b) DMA xt window LAST (rows h-2..h+5, cols wbase-2..wbase+33) --
#pragma unroll
    for (int i = 0; i < 5; ++i) {
        int jb = i * 512 + wv * 64;
        if (jb < 2304) {             // 288 lins x 8 chunks
            int j = jb + l;
            int lin = j >> 3, slot = j & 7;
            int cidx = (slot - lin) & 7;
            int row = lin / 36, col = lin - row * 36;
            int rs = min(max(h - 2 + row, 0), Hn - 1);
            int cs = min(max(wbase - 2 + col, 0), Wn - 1);
            const ushort* gp = xt_b + (size_t)(rs * Wn + cs) * Cn + cidx * 8;
            __builtin_amdgcn_global_load_lds(
                (const __attribute__((address_space(1))) unsigned int*)gp,
                (__attribute__((address_space(3))) unsigned int*)(s_win + (size_t)jb * 8),
                16, 0, 0);
        }
    }
    // drain ft for every wave (min xt in flight = 4); xt stays in flight
    asm volatile("s_waitcnt vmcnt(4)" ::: "memory");
    __builtin_amdgcn_s_barrier();  // (1) ft window ready for all waves

    f32x4 zero = {0.f, 0.f, 0.f, 0.f};
    s16x8 zz = {0, 0, 0, 0, 0, 0, 0, 0};

    // ---- phase 1: om GEMM from ft window (M=128 px, N=32 ocp, K=576) ----
    f32x4 acc2[2];
    acc2[0] = zero; acc2[1] = zero;
    {
        int pxg = wv * 16 + r;            // GEMM M-index (block-local px)
        int rg = pxg >> 5, cg = pxg & 31;
#pragma unroll 3
        for (int k = 0; k < 9; ++k) {
            int dy = k / 3 - 1, dx = k % 3 - 1;
            int y = h + rg + dy;
            bool yv = (y >= 0) && (y < Hn);
            int xx = wbase + cg + dx;
            bool valid = yv && (xx >= 0) && (xx < Wn);
            int lin = (rg + dy + 1) * 36 + cg + dx + 2;
#pragma unroll
            for (int s = 0; s < 2; ++s) {
                int c = s * 4 + q;
                s16x8 av = *(const s16x8*)&s_ft[lin * 64 + (((c + lin) & 7) << 3)];
                av = valid ? av : zz;
#pragma unroll
                for (int ot = 0; ot < 2; ++ot) {
                    s16x8 bv = *(const s16x8*)(woT2 + (size_t)s * 9216
                                               + (size_t)(k * 32 + ot * 16 + r) * 32 + q * 8);
                    acc2[ot] = __builtin_amdgcn_mfma_f32_16x16x32_bf16(av, bv, acc2[ot], 0, 0, 0);
                }
            }
        }
    }
    __syncthreads();  // (2) ft reads done; region becomes s_om

    // ---- bounce: bias + sigmoid -> s_om[27][128] ----
#pragma unroll
    for (int ot = 0; ot < 2; ++ot) {
        int oc = ot * 16 + r;
        if (oc < 27) {
            float bo = b_off[oc];
#pragma unroll
            for (int reg = 0; reg < 4; ++reg) {
                int p = wv * 16 + q * 4 + reg;
                float v = acc2[ot][reg] + bo;
                if (oc >= 18) v = 1.f / (1.f + __expf(-v));
                s_om[oc * 128 + p] = v;
            }
        }
    }
    __syncthreads();  // (3) s_om visible; drains xt DMA (vmcnt 0)

    // ---- per-lane om values + vote ----
    float omv[27];
#pragma unroll
    for (int o = 0; o < 27; ++o) omv[o] = s_om[o * 128 + rowoff * 32 + pxi];
    bool okp = true;
#pragma unroll
    for (int k = 0; k < 9; ++k) {
        float uy = (float)(k / 3 - 1) + omv[9 + k];
        float ux = pxif + (float)(k % 3 - 1) + omv[k];
        okp = okp && (uy >= -2.f - rowofff) && (uy < 5.f - rowofff)
                  && (ux >= -2.f) && (ux < 33.f);
    }
    int fast = __all(okp) ? 1 : 0;

    f32x4 acc[4];
    acc[0] = zero; acc[1] = zero; acc[2] = zero; acc[3] = zero;

    if (fast) {
#pragma unroll 3
        for (int k = 0; k < 9; ++k) {
            float uy = (float)(k / 3 - 1) + omv[9 + k];
            float ux = pxif + (float)(k % 3 - 1) + omv[k];
            float mv = omv[18 + k];
            float y0f = floorf(uy), x0f = floorf(ux);
            float fy = uy - y0f, fx = ux - x0f;
            int iy = (int)y0f + 2 + rowoff;  // 0..6
            int ix = (int)x0f + 2;           // 0..34
            int yab = hrow + (int)y0f, xab = wbase + (int)x0f;
            bool vy0 = (yab >= 0) && (yab < Hn);
            bool vy1 = (yab + 1 >= 0) && (yab + 1 < Hn);
            bool vx0 = (xab >= 0) && (xab < Wn);
            bool vx1 = (xab + 1 >= 0) && (xab + 1 < Wn);
            float g0 = (vy0 && vx0) ? (1.f - fy) * (1.f - fx) * mv : 0.f;
            float g1 = (vy0 && vx1) ? (1.f - fy) * fx * mv : 0.f;
            float g2 = (vy1 && vx0) ? fy * (1.f - fx) * mv : 0.f;
            float g3 = (vy1 && vx1) ? fy * fx * mv : 0.f;
            int l0 = iy * 36 + ix, l1 = l0 + 1, l2 = l0 + 36, l3 = l0 + 37;
            // weights for this tap (global, L2-hot): full 64 oc
            s16x8 bw[2][4];
#pragma unroll
            for (int s = 0; s < 2; ++s)
#pragma unroll
                for (int ot = 0; ot < 4; ++ot)
                    bw[s][ot] = *(const s16x8*)(wdT2 + (size_t)s * 18432
                                                + (size_t)(k * 64 + ot * 16 + r) * 32 + q * 8);
            s16x8 af[2];
#pragma unroll
            for (int s = 0; s < 2; ++s) {
                int c = s * 4 + q;  // logical chunk
                s16x8 q0 = *(const s16x8*)&s_win[l0 * 64 + (((c + l0) & 7) << 3)];
                s16x8 q1 = *(const s16x8*)&s_win[l1 * 64 + (((c + l1) & 7) << 3)];
                s16x8 q2 = *(const s16x8*)&s_win[l2 * 64 + (((c + l2) & 7) << 3)];
                s16x8 q3 = *(const s16x8*)&s_win[l3 * 64 + (((c + l3) & 7) << 3)];
                s16x8 p;
#pragma unroll
                for (int j = 0; j < 8; ++j) {
                    float rr = g0 * bf2f((unsigned short)q0[j]) + g1 * bf2f((unsigned short)q1[j])
                             + g2 * bf2f((unsigned short)q2[j]) + g3 * bf2f((unsigned short)q3[j]);
                    p[j] = (short)f2bf(rr);
                }
                af[s] = p;
            }
#pragma unroll
            for (int s = 0; s < 2; ++s)
#pragma unroll
                for (int ot = 0; ot < 4; ++ot)
                    acc[ot] = __builtin_amdgcn_mfma_f32_16x16x32_bf16(af[s], bw[s][ot], acc[ot], 0, 0, 0);
        }
    } else {
        // slow path (rare, any-input correct): global gathers + global weights
#pragma unroll 1
        for (int k = 0; k < 9; ++k) {
            float ys = (float)(hrow + k / 3 - 1) + omv[9 + k];
            float xs = (float)(wbase + pxi + k % 3 - 1) + omv[k];
            float mv = omv[18 + k];
            float y0f = floorf(ys), x0f = floorf(xs);
            float fy = ys - y0f, fx = xs - x0f;
            int y0 = (int)y0f, x0 = (int)x0f;
            float g[4];
            int a[4];
#pragma unroll
            for (int n = 0; n < 4; ++n) {
                int yy = y0 + (n >> 1), xx = x0 + (n & 1);
                bool valid = (yy >= 0) && (yy < Hn) && (xx >= 0) && (xx < Wn);
                float wgt = ((n >> 1) ? fy : 1.f - fy) * ((n & 1) ? fx : 1.f - fx) * mv;
                g[n] = valid ? wgt : 0.f;
                int yc = min(max(yy, 0), Hn - 1), xc = min(max(xx, 0), Wn - 1);
                a[n] = (yc * Wn + xc) * Cn;
            }
#pragma unroll
            for (int s = 0; s < 2; ++s) {
                int c = s * 32 + q * 8;
                s16x8 q0 = *(const s16x8*)(xt_b + a[0] + c);
                s16x8 q1 = *(const s16x8*)(xt_b + a[1] + c);
                s16x8 q2 = *(const s16x8*)(xt_b + a[2] + c);
                s16x8 q3 = *(const s16x8*)(xt_b + a[3] + c);
                s16x8 af;
#pragma unroll
                for (int j = 0; j < 8; ++j) {
                    float rr = g[0] * bf2f((unsigned short)q0[j]) + g[1] * bf2f((unsigned short)q1[j])
                             + g[2] * bf2f((unsigned short)q2[j]) + g[3] * bf2f((unsigned short)q3[j]);
                    af[j] = (short)f2bf(rr);
                }
#pragma unroll
                for (int ot = 0; ot < 4; ++ot) {
                    s16x8 bv = *(const s16x8*)(wdT2 + (size_t)s * 18432
                                               + (size_t)(k * 64 + ot * 16 + r) * 32 + q * 8);
                    acc[ot] = __builtin_amdgcn_mfma_f32_16x16x32_bf16(af, bv, acc[ot], 0, 0, 0);
                }
            }
        }
    }

    // ---- epilogue: bias + ReLU, DIRECT aligned f32x4 stores (no LDS
    //      bounce, no barriers); L2 write-combines the 16-B pieces. ----
    {
        float* ob = out + (size_t)b * On * HWn + (size_t)hrow * Wn + wbase + pxh * 16 + q * 4;
#pragma unroll
        for (int ot = 0; ot < 4; ++ot) {
            int oc = ot * 16 + r;
            float bv = b_def[oc];
            f32x4 vv;
#pragma unroll
            for (int reg = 0; reg < 4; ++reg) vv[reg] = fmaxf(acc[ot][reg] + bv, 0.f);
            *(f32x4*)(ob + (size_t)oc * HWn) = vv;
        }
    }
}

// ---------------------------------------------------------------------------
extern "C" void kernel_launch(void* const* d_in, const int* in_sizes, int n_in,
                              void* d_out, int out_size, void* d_ws, size_t ws_size,
                              hipStream_t stream) {
    const float* x = (const float*)d_in[0];
    const float* feat = (const float*)d_in[1];
    const float* w_off = (const float*)d_in[2];
    const float* b_off = (const float*)d_in[3];
    const float* w_def = (const float*)d_in[4];
    const float* b_def = (const float*)d_in[5];
    float* out = (float*)d_out;

    char* ws = (char*)d_ws;
    ushort* xt = (ushort*)ws;                           // 8 MB [B,HW,C] bf16
    ushort* ft = (ushort*)(ws + 8388608);               // 8 MB [B,HW,C] bf16
    ushort* wdT2 = (ushort*)(ws + 16777216);            // 73728 B [2][9][64][32]
    ushort* woT2 = (ushort*)(ws + 16850944);            // 36864 B [2][9][32][32]

    hipLaunchKernelGGL(transpose_all, dim3(HWn / 64, Bn, 3), dim3(256), 0, stream,
                       x, feat, w_def, w_off, xt, ft, wdT2, woT2);
    hipLaunchKernelGGL(mega_kernel, dim3((Bn * HWn) / 128), dim3(512), 0, stream,
                       xt, ft, wdT2, woT2, b_off, b_def, out);
}